// Round 15
// baseline (876.486 us; speedup 1.0000x reference)
//
#include <hip/hip_runtime.h>

// ---------------------------------------------------------------------------
// Spiking VGG9, 10 steps, B=128.  R15: R13 + fully-unrolled tap loop.
//  - u-loop #pragma unroll (U<=36): q/slab/buffer-parity compile-time ->
//    all ds_read/gl_lds addresses fold to base+immediate (VALU/tap ~ 0)
//  - launch_bounds back to (512,4) (R14's 6 thrashed L2: FETCH 66->167MB)
//  - int64 epilogue fold kept (bit-identical, fewer live registers)
//  - all else identical to R13 (8-wave 128px x 64oc blocks, 32x32 wave
//    tiles, i8 3-digit exact weights, mfma_i32_16x16x64_i8)
// ---------------------------------------------------------------------------

typedef __attribute__((ext_vector_type(4))) int int32x4;

__device__ __forceinline__ float bf2f(ushort h) {
    union { unsigned u; float f; } v; v.u = ((unsigned)h) << 16;
    return v.f;
}
constexpr int ilog2(int x) { int r = 0; while (x > 1) { x >>= 1; ++r; } return r; }

__device__ __forceinline__ void gl_lds16(const void* g, void* l) {
    __builtin_amdgcn_global_load_lds(
        (const __attribute__((address_space(1))) unsigned int*)g,
        (__attribute__((address_space(3))) unsigned int*)l, 16, 0, 0);
}

#define SC21 4.76837158203125e-07    // 2^-21  (acts are spikes {0,1})
#define SC23 1.1920928955078125e-07  // 2^-23  (acts are ints 0..4 = 4*act)

// ------------------------------------------------------------ weight prep --
template <int IC, int OC>
__global__ void prep_convw_i8_k(const float* __restrict__ w, char* __restrict__ dst) {
    int idx = blockIdx.x * 256 + threadIdx.x;
    if (idx >= OC * IC * 9) return;
    int oc = idx / (IC * 9);
    int rem = idx % (IC * 9);
    int ic = rem / 9, q = rem % 9;
    int wq_ = (int)rintf(w[idx] * 2097152.0f);   // 2^21 grid
    int a2 = ((wq_ + 128) & 255) - 128;
    int t2 = (wq_ - a2) >> 8;
    int a1 = ((t2 + 128) & 255) - 128;
    int a0 = (t2 - a1) >> 8;
    int sg = ic >> 6, kin = ic & 63, c = kin >> 4, bb = kin & 15;
    int oct = oc >> 6, ocl = oc & 63;
    constexpr int OCT = OC / 64;
    size_t base = ((size_t)(sg * 9 + q) * OCT + oct) * 12288;
    char digs[3] = {(char)a0, (char)a1, (char)a2};
#pragma unroll
    for (int s = 0; s < 3; ++s)
        dst[base + (size_t)(c * 192 + s * 64 + ocl) * 16 + bb] = digs[s];
}

__global__ void prep_fc1w_i8_k(const float* __restrict__ w, char* __restrict__ dst) {
    int idx = blockIdx.x * 256 + threadIdx.x;
    if (idx >= 1024 * 4096) return;
    int j = idx >> 12, k = idx & 4095;
    int c = k >> 4, hw = k & 15;
    int kp = hw * 256 + c;
    int wq_ = (int)rintf(w[idx] * 2097152.0f);
    int a2 = ((wq_ + 128) & 255) - 128;
    int t2 = (wq_ - a2) >> 8;
    int a1 = ((t2 + 128) & 255) - 128;
    int a0 = (t2 - a1) >> 8;
    int slab = kp >> 6, kin = kp & 63, cch = kin >> 4, bb = kin & 15;
    int oct = j >> 6, ocl = j & 63;
    size_t base = ((size_t)(slab * 16 + oct)) * 12288;
    char digs[3] = {(char)a0, (char)a1, (char)a2};
#pragma unroll
    for (int s = 0; s < 3; ++s)
        dst[base + (size_t)(cch * 192 + s * 64 + ocl) * 16 + bb] = digs[s];
}

// ------------------------------------------------------------- halo zero ----
template <int H, int C>
__global__ void halo0_k(char* __restrict__ buf) {
    constexpr int P = 4 * H + 4;
    constexpr int CPI = P * (C / 16);
    int idx = blockIdx.x * 256 + threadIdx.x;
    if (idx >= 1280 * CPI) return;
    int n = idx / CPI, r = idx % CPI;
    int p = r / (C / 16), c16 = r % (C / 16);
    int row, col;
    if (p < 2 * (H + 2)) { row = (p < H + 2) ? 0 : H + 1; col = p % (H + 2); }
    else { int qq = p - 2 * (H + 2); col = (qq < H) ? 0 : H + 1; row = 1 + (qq % H); }
    *(uint4*)&buf[(((size_t)n * (H + 2) + row) * (H + 2) + col) * C + c16 * 16] =
        (uint4){0u, 0u, 0u, 0u};
}

// ------------------------------------------------- conv1 + 10-step LIF ------
__global__ __launch_bounds__(256) void conv1lif_k(const float* __restrict__ inp,
                                                  const float* __restrict__ w1,
                                                  char* __restrict__ act1) {
    __shared__ float ws[27 * 64];
    for (int e = threadIdx.x; e < 1728; e += 256) {
        int oc = e / 27, j = e % 27;
        ws[j * 64 + oc] = w1[e];
    }
    __syncthreads();
    int t = blockIdx.x * 256 + threadIdx.x;
    int q = t & 3;
    int m = t >> 2;
    int n = m >> 10, h = (m >> 5) & 31, w = m & 31;
    float xv[27];
#pragma unroll
    for (int ic = 0; ic < 3; ++ic)
#pragma unroll
        for (int kh = 0; kh < 3; ++kh)
#pragma unroll
            for (int kw = 0; kw < 3; ++kw) {
                int r = h + kh - 1, c = w + kw - 1;
                xv[ic * 9 + kh * 3 + kw] =
                    (r >= 0 && r < 32 && c >= 0 && c < 32)
                        ? inp[(n * 3 + ic) * 1024 + r * 32 + c] : 0.0f;
            }
    float s[16], mem[16];
#pragma unroll
    for (int o = 0; o < 16; ++o) { s[o] = 0.f; mem[o] = 0.f; }
#pragma unroll
    for (int j = 0; j < 27; ++j) {
        float x = xv[j];
        const float* wr = &ws[j * 64 + q * 16];
#pragma unroll
        for (int o = 0; o < 16; ++o) s[o] += wr[o] * x;
    }
    const size_t dbase = (((size_t)h + 1) * 34 + (w + 1)) * 64 + q * 16;
    for (int st = 0; st < 10; ++st) {
        unsigned r[4];
#pragma unroll
        for (int g = 0; g < 4; ++g) {
            unsigned acc = 0;
#pragma unroll
            for (int e = 0; e < 4; ++e) {
                int o = g * 4 + e;
                mem[o] = 0.05f * mem[o] + 0.95f * s[o];
                unsigned b = (mem[o] > 1.f) ? 1u : 0u;
                mem[o] -= (float)b;
                acc |= b << (8 * e);
            }
            r[g] = acc;
        }
        size_t d = ((size_t)(st * 128 + n) * 34 * 34) * 64 + dbase;
        *(uint4*)&act1[d] = (uint4){r[0], r[1], r[2], r[3]};
    }
}

// --------------------------------------------------- i8 implicit-GEMM conv --
// 512 threads / 8 waves (4m x 2n); wave tile 32px x 32oc; MBLK = 128 px.
// Fully-unrolled tap loop: LDS addresses fold to base + immediate.
template <int H, int W, int IC, int OC, int NI, int MR, int EPI>
__global__ __launch_bounds__(512, 4) void convi8_k(const char* __restrict__ act,
                                                   const char* __restrict__ wq,
                                                   char* __restrict__ outs,
                                                   float scale) {
    constexpr int PW = W + 2, PHR = MR + 2;
    constexpr int MBLK = NI * MR * W;
    constexpr int NPIX = NI * PHR * PW;
    constexpr int ACH = NPIX * 4;
    constexpr int HR = (ACH + 511) / 512;
    constexpr int SLABS = IC / 64;
    constexpr int OCT = OC / 64;
    constexpr int U = SLABS * 9;
    constexpr int LHW = ilog2(H * W), LW2 = ilog2(W), LMW = ilog2(MR * W);
    static_assert(MBLK == 128, "tile mapping");

    __shared__ __align__(16) char sA[NPIX * 64];
    __shared__ __align__(16) char sB[2][12288];

    const int tid = threadIdx.x, lane = tid & 63;
    const int wid = tid >> 6;                    // 0..7
    const int wm = wid >> 1, wn = wid & 1;       // 4m x 2n
    const int b = blockIdx.x, oct = blockIdx.y;
    const int oc0 = oct * 64;
    const int m0 = b * MBLK;
    constexpr int TPI = (NI == 1) ? (H / MR) : 1;
    const int n0 = (NI == 1) ? (b / TPI) : (b * NI);
    const int h0 = (NI == 1) ? (b % TPI) * MR : 0;

    int asrc[HR]; bool apred[HR];
#pragma unroll
    for (int r = 0; r < HR; ++r) {
        int i = r * 512 + tid;
        apred[r] = (i < ACH);
        int ii = apred[r] ? i : 0;
        int c = ii / NPIX, pix = ii % NPIX;
        int pc = pix % PW, t2 = pix / PW;
        int hp = t2 % PHR, img = t2 / PHR;
        asrc[r] = (((n0 + img) * (H + 2) + h0 + hp) * PW + pc) * IC + c * 16;
    }
    const int lan15 = lane & 15;
    int apix[2];
#pragma unroll
    for (int am = 0; am < 2; ++am) {
        int p = wm * 32 + am * 16 + lan15;
        int img = p >> LMW;
        int pi = p & ((MR * W) - 1);
        int h = pi >> LW2;
        apix[am] = (img * PHR + h) * PW + (pi & (W - 1));
    }
    const int cA = lane >> 4;

    int32x4 acc[3][2][2];
#pragma unroll
    for (int s = 0; s < 3; ++s)
#pragma unroll
        for (int a = 0; a < 2; ++a)
#pragma unroll
            for (int bn = 0; bn < 2; ++bn) acc[s][a][bn] = (int32x4){0, 0, 0, 0};

    const size_t wqoct = (size_t)oct * 12288;
    constexpr size_t USTRIDE = (size_t)OCT * 12288;

    auto stage_B = [&](int unit, int bufc) {
        const char* wsrc = wq + (size_t)unit * USTRIDE + wqoct;
        gl_lds16(wsrc + tid * 16, sB[bufc] + tid * 16);          // chunks 0..511
        if (tid < 256)
            gl_lds16(wsrc + 8192 + tid * 16, sB[bufc] + 8192 + tid * 16);
    };
    auto stage_A = [&](int sl_) {
#pragma unroll
        for (int r = 0; r < HR; ++r)
            if (apred[r]) gl_lds16(act + asrc[r] + sl_ * 64, sA + (r * 512 + tid) * 16);
    };

    stage_A(0);
    stage_B(0, 0);
    __syncthreads();

    // thread-constant LDS base offsets (byte): tap offsets become immediates
    const int afbase0 = (cA * NPIX + apix[0]) * 16;
    const int afbase1 = (cA * NPIX + apix[1]) * 16;
    const int bfbase  = (cA * 192 + wn * 32 + lan15) * 16;

#pragma unroll
    for (int u = 0; u < U; ++u) {
        const int q = u - (u / 9) * 9;
        if (u + 1 < U) stage_B(u + 1, (u + 1) & 1);
        const int qr = q / 3, qc = q - qr * 3;
        const int tapoff = (qr * PW + qc) * 16;     // compile-time under unroll
        int32x4 af[2];
        af[0] = *(const int32x4*)&sA[afbase0 + tapoff];
        af[1] = *(const int32x4*)&sA[afbase1 + tapoff];
        __builtin_amdgcn_s_setprio(1);
#pragma unroll
        for (int s = 0; s < 3; ++s)
#pragma unroll
            for (int bn = 0; bn < 2; ++bn) {
                int32x4 bf = *(const int32x4*)&sB[u & 1][bfbase + s * 1024 + bn * 256];
#pragma unroll
                for (int am = 0; am < 2; ++am)
                    acc[s][am][bn] = __builtin_amdgcn_mfma_i32_16x16x64_i8(
                        af[am], bf, acc[s][am][bn], 0, 0, 0);
            }
        __builtin_amdgcn_s_setprio(0);
        __syncthreads();          // drains stage(u+1); certifies buffer swap
        if (q == 8 && u + 1 < U) {
            stage_A(u / 9 + 1);   // sA readers retired at the barrier above
            __syncthreads();      // drain halo restage before next tap-0
        }
    }

    const double dscale = (double)scale;
#pragma unroll
    for (int am = 0; am < 2; ++am)
#pragma unroll
        for (int bn = 0; bn < 2; ++bn)
#pragma unroll
            for (int rr = 0; rr < 4; ++rr) {
                int rl = wm * 32 + am * 16 + (lane >> 4) * 4 + rr;
                int col = oc0 + wn * 32 + bn * 16 + lan15;
                int m = m0 + rl;
                long long S = ((long long)acc[0][am][bn][rr] << 16)
                            + ((long long)acc[1][am][bn][rr] << 8)
                            + (long long)acc[2][am][bn][rr];
                float v = (float)((double)S * dscale);
                char sp = (v > 1.0f) ? (char)1 : (char)0;
                if (EPI == 1) {
                    int n = m >> LHW, h = (m >> LW2) & (H - 1), w = m & (W - 1);
                    outs[((size_t)(n * (H + 2) + h + 1) * PW + (w + 1)) * OC + col] = sp;
                } else {
                    outs[(size_t)m * OC + col] = sp;
                }
            }
}

// ------------------------------------------------------------- i8 pool ----
template <int C, int HI>
__global__ void pool_i8_k(const char* __restrict__ in, char* __restrict__ out) {
    constexpr int HO = HI / 2, C16 = C / 16;
    constexpr int TOT = 1280 * HO * HO * C16;
    int idx = blockIdx.x * 256 + threadIdx.x;
    if (idx >= TOT) return;
    int c16 = idx % C16;
    int t = idx / C16;
    int w = t % HO; t /= HO;
    int h = t % HO;
    int n = t / HO;
    const char* p = in + ((size_t)(n * HI + 2 * h) * HI + 2 * w) * C + c16 * 16;
    uint4 a0 = *(const uint4*)p;
    uint4 a1 = *(const uint4*)(p + C);
    uint4 a2 = *(const uint4*)(p + (size_t)HI * C);
    uint4 a3 = *(const uint4*)(p + (size_t)HI * C + C);
    uint4 r;
    r.x = a0.x + a1.x + a2.x + a3.x;
    r.y = a0.y + a1.y + a2.y + a3.y;
    r.z = a0.z + a1.z + a2.z + a3.z;
    r.w = a0.w + a1.w + a2.w + a3.w;
    *(uint4*)&out[((size_t)(n * (HO + 2) + h + 1) * (HO + 2) + (w + 1)) * C + c16 * 16] = r;
}

__global__ void pool3q_k(const char* __restrict__ in, char* __restrict__ out) {
    int idx = blockIdx.x * 256 + threadIdx.x;   // 327680
    if (idx >= 327680) return;
    int c16 = idx & 15;
    int t = idx >> 4;
    int wo = t & 3, ho = (t >> 2) & 3, n = t >> 4;
    const char* p = in + ((size_t)(n * 8 + 2 * ho) * 8 + 2 * wo) * 256 + c16 * 16;
    uint4 a0 = *(const uint4*)p;
    uint4 a1 = *(const uint4*)(p + 256);
    uint4 a2 = *(const uint4*)(p + 2048);
    uint4 a3 = *(const uint4*)(p + 2048 + 256);
    uint4 r;
    r.x = a0.x + a1.x + a2.x + a3.x;
    r.y = a0.y + a1.y + a2.y + a3.y;
    r.z = a0.z + a1.z + a2.z + a3.z;
    r.w = a0.w + a1.w + a2.w + a3.w;
    *(uint4*)&out[((size_t)(n * 16 + ho * 4 + wo) * 16 + c16) * 16] = r;
}

// ----------------------------------------------------------- fc1 i8 GEMM ----
__global__ __launch_bounds__(256) void fc1i8_k(const char* __restrict__ A,
                                               const char* __restrict__ wq,
                                               float* __restrict__ part) {
    __shared__ __align__(16) char sA[2][8192];
    __shared__ __align__(16) char sB[2][12288];
    const int tid = threadIdx.x, lane = tid & 63;
    const int wid = tid >> 6, wm = wid >> 1, wn = wid & 1;
    const int m0 = blockIdx.x * 128, oct = blockIdx.y, kt = blockIdx.z;

    int32x4 acc[3][4][2];
#pragma unroll
    for (int s = 0; s < 3; ++s)
#pragma unroll
        for (int a = 0; a < 4; ++a)
#pragma unroll
            for (int bn = 0; bn < 2; ++bn) acc[s][a][bn] = (int32x4){0, 0, 0, 0};

    auto stageA = [&](int sg, int bf_) {
#pragma unroll
        for (int r = 0; r < 2; ++r) {
            int i = r * 256 + tid;
            int c = i >> 7, pix = i & 127;
            gl_lds16(A + (size_t)(m0 + pix) * 4096 + sg * 64 + c * 16,
                     sA[bf_] + (size_t)i * 16);
        }
    };
    auto stageB = [&](int sg, int bf_) {
        const char* src = wq + ((size_t)(sg * 16 + oct)) * 12288 + tid * 16;
#pragma unroll
        for (int r = 0; r < 3; ++r)
            gl_lds16(src + r * 4096, sB[bf_] + (r * 256 + tid) * 16);
    };

    int buf = 0;
    stageA(kt * 32, 0);
    stageB(kt * 32, 0);
    __syncthreads();
    const int cA = lane >> 4;
    for (int sl = 0; sl < 32; ++sl) {
        int sg = kt * 32 + sl;
        if (sl < 31) { stageA(sg + 1, buf ^ 1); stageB(sg + 1, buf ^ 1); }
        int32x4 af[4];
#pragma unroll
        for (int am = 0; am < 4; ++am)
            af[am] = *(const int32x4*)&sA[buf][(cA * 128 + wm * 64 + am * 16 + (lane & 15)) * 16];
#pragma unroll
        for (int s = 0; s < 3; ++s)
#pragma unroll
            for (int bn = 0; bn < 2; ++bn) {
                int R = s * 64 + wn * 32 + bn * 16 + (lane & 15);
                int32x4 bf = *(const int32x4*)&sB[buf][(cA * 192 + R) * 16];
#pragma unroll
                for (int am = 0; am < 4; ++am)
                    acc[s][am][bn] = __builtin_amdgcn_mfma_i32_16x16x64_i8(
                        af[am], bf, acc[s][am][bn], 0, 0, 0);
            }
        if (sl < 31) { __syncthreads(); buf ^= 1; }
    }
#pragma unroll
    for (int am = 0; am < 4; ++am)
#pragma unroll
        for (int bn = 0; bn < 2; ++bn)
#pragma unroll
            for (int rr = 0; rr < 4; ++rr) {
                int row = m0 + wm * 64 + am * 16 + (lane >> 4) * 4 + rr;
                int col = oct * 64 + wn * 32 + bn * 16 + (lane & 15);
                long long S = ((long long)acc[0][am][bn][rr] << 16)
                            + ((long long)acc[1][am][bn][rr] << 8)
                            + (long long)acc[2][am][bn][rr];
                part[((size_t)kt * 1280 + row) * 1024 + col] = (float)((double)S * SC23);
            }
}

__global__ void fc1lif_k(const float* __restrict__ part, ushort* __restrict__ sbuf) {
    int idx = blockIdx.x * 256 + threadIdx.x;   // 131072
    int n = idx >> 10, j = idx & 1023;
    float m = 0.f;
    for (int t = 0; t < 10; ++t) {
        size_t row = (size_t)(t * 128 + n) * 1024 + j;
        float y = part[row] + part[1310720 + row];
        m = 0.05f * m + 0.95f * y;
        float sp = (m > 1.f) ? 1.f : 0.f;
        m -= sp;
        sbuf[row] = sp > 0.f ? (ushort)0x3F80 : (ushort)0;
    }
}

__global__ __launch_bounds__(256) void fc2o_k(const ushort* __restrict__ S,
                                              const float* __restrict__ W2,
                                              float* __restrict__ out) {
    __shared__ float wsh[10 * 1024];
    __shared__ float red[10][256];
    int n = blockIdx.x, tid = threadIdx.x;
    for (int e = tid; e < 10240; e += 256) wsh[e] = W2[e];
    __syncthreads();
    float accv = 0.f;
    for (int t = 0; t < 10; ++t) {
        const ushort* sp = S + ((size_t)(t * 128 + n)) * 1024 + tid * 4;
        float s0 = bf2f(sp[0]), s1 = bf2f(sp[1]), s2 = bf2f(sp[2]), s3 = bf2f(sp[3]);
#pragma unroll
        for (int o = 0; o < 10; ++o) {
            const float* w = &wsh[o * 1024 + tid * 4];
            red[o][tid] = s0 * w[0] + s1 * w[1] + s2 * w[2] + s3 * w[3];
        }
        __syncthreads();
        for (int off = 128; off >= 1; off >>= 1) {
            if (tid < off) {
#pragma unroll
                for (int o = 0; o < 10; ++o) red[o][tid] += red[o][tid + off];
            }
            __syncthreads();
        }
        if (tid < 10) accv += red[tid][0];
        __syncthreads();
    }
    if (tid < 10) out[n * 10 + tid] = accv * 0.1f;
}

// ---------------------------------------------------------------------------
extern "C" void kernel_launch(void* const* d_in, const int* in_sizes, int n_in,
                              void* d_out, int out_size, void* d_ws, size_t ws_size,
                              hipStream_t stream) {
    const float* inp  = (const float*)d_in[0];
    const float* w1   = (const float*)d_in[1];
    const float* w2   = (const float*)d_in[2];
    const float* w3   = (const float*)d_in[3];
    const float* w4   = (const float*)d_in[4];
    const float* w5   = (const float*)d_in[5];
    const float* w6   = (const float*)d_in[6];
    const float* w7   = (const float*)d_in[7];
    const float* fc1w = (const float*)d_in[8];
    const float* fc2w = (const float*)d_in[9];
    float* out = (float*)d_out;

    char* base = (char*)d_ws;
    char* arenaA = base;                          // 94,679,040 B
    char* arenaB = base + 94679040;               // 83,886,080 B
    size_t o = 94679040 + 83886080;
    auto alloc = [&](size_t bytes) { void* p = base + o; o += (bytes + 255) & ~(size_t)255; return p; };
    char*   wq2  = (char*)alloc(110592);
    char*   wq3  = (char*)alloc(221184);
    char*   wq4  = (char*)alloc(442368);
    char*   wq5  = (char*)alloc(884736);
    char*   wq6  = (char*)alloc(1769472);
    char*   wq7  = (char*)alloc(1769472);
    char*   wqf1 = (char*)alloc(12582912);
    ushort* sbuf = (ushort*)alloc(2621440);
    (void)ws_size;

    char*  act1  = arenaA;                        // [1280][34][34][64]
    char*  c2out = arenaB;                        // [1280][32][32][64]
    char*  act2  = arenaA;                        // [1280][18][18][64]
    char*  c3out = arenaB;                        // [1280][18][18][128]
    char*  c4out = arenaA;                        // [1280][16][16][128]
    char*  act3  = arenaA + 41943040;             // [1280][10][10][128]
    char*  c5out = arenaB;                        // [1280][10][10][256]
    char*  c6out = arenaB + 33554432;             // [1280][10][10][256]
    char*  c7out = arenaA;                        // [1280][8][8][256]
    char*  afc1  = arenaA + 20971520;             // [1280][4096] i8
    float* part  = (float*)(arenaA + 26214400);   // [2][1280][1024] f32

    prep_convw_i8_k<64, 64>  <<<(36864 + 255) / 256, 256, 0, stream>>>(w2, wq2);
    prep_convw_i8_k<64, 128> <<<(73728 + 255) / 256, 256, 0, stream>>>(w3, wq3);
    prep_convw_i8_k<128, 128><<<(147456 + 255) / 256, 256, 0, stream>>>(w4, wq4);
    prep_convw_i8_k<128, 256><<<(294912 + 255) / 256, 256, 0, stream>>>(w5, wq5);
    prep_convw_i8_k<256, 256><<<(589824 + 255) / 256, 256, 0, stream>>>(w6, wq6);
    prep_convw_i8_k<256, 256><<<(589824 + 255) / 256, 256, 0, stream>>>(w7, wq7);
    prep_fc1w_i8_k<<<(4194304 + 255) / 256, 256, 0, stream>>>(fc1w, wqf1);

    halo0_k<32, 64><<<(1280 * 132 * 4 + 255) / 256, 256, 0, stream>>>(act1);
    conv1lif_k<<<2048, 256, 0, stream>>>(inp, w1, act1);

    convi8_k<32, 32, 64, 64, 1, 4, 0>
        <<<dim3(10240, 1), 512, 0, stream>>>(act1, wq2, c2out, (float)SC21);
    halo0_k<16, 64><<<(1280 * 68 * 4 + 255) / 256, 256, 0, stream>>>(act2);
    pool_i8_k<64, 32><<<(1280 * 256 * 4 + 255) / 256, 256, 0, stream>>>(c2out, act2);

    halo0_k<16, 128><<<(1280 * 68 * 8 + 255) / 256, 256, 0, stream>>>(c3out);
    convi8_k<16, 16, 64, 128, 1, 8, 1>
        <<<dim3(2560, 2), 512, 0, stream>>>(act2, wq3, c3out, (float)SC23);
    convi8_k<16, 16, 128, 128, 1, 8, 0>
        <<<dim3(2560, 2), 512, 0, stream>>>(c3out, wq4, c4out, (float)SC21);
    halo0_k<8, 128><<<(1280 * 36 * 8 + 255) / 256, 256, 0, stream>>>(act3);
    pool_i8_k<128, 16><<<(1280 * 64 * 8 + 255) / 256, 256, 0, stream>>>(c4out, act3);

    halo0_k<8, 256><<<(1280 * 36 * 16 + 255) / 256, 256, 0, stream>>>(c5out);
    convi8_k<8, 8, 128, 256, 2, 8, 1>
        <<<dim3(640, 4), 512, 0, stream>>>(act3, wq5, c5out, (float)SC23);
    halo0_k<8, 256><<<(1280 * 36 * 16 + 255) / 256, 256, 0, stream>>>(c6out);
    convi8_k<8, 8, 256, 256, 2, 8, 1>
        <<<dim3(640, 4), 512, 0, stream>>>(c5out, wq6, c6out, (float)SC21);
    convi8_k<8, 8, 256, 256, 2, 8, 0>
        <<<dim3(640, 4), 512, 0, stream>>>(c6out, wq7, c7out, (float)SC21);

    pool3q_k<<<(327680 + 255) / 256, 256, 0, stream>>>(c7out, afc1);

    fc1i8_k<<<dim3(10, 16, 2), 256, 0, stream>>>(afc1, wqf1, part);
    fc1lif_k<<<512, 256, 0, stream>>>(part, sbuf);
    fc2o_k<<<128, 256, 0, stream>>>(sbuf, fc2w, out);
}

// Round 16
// 795.957 us; speedup vs baseline: 1.1012x; 1.1012x over previous
//
#include <hip/hip_runtime.h>

// ---------------------------------------------------------------------------
// Spiking VGG9, 10 steps, B=128.  R16: LDS-balanced wave tile (64px x 32oc).
//  - R13 analysis: LDS-read pipe was ~80% busy (6KB B-frag reads per tap per
//    wave vs only 12 MFMA).  am=4 doubles MFMA per B-read -> pipes balanced.
//  - 4-wave 256-thread blocks + __launch_bounds__(256,3): acc=96 fits under
//    170 VGPR -> 3 blocks/CU = 3 waves/SIMD (R7's same tile ran at 2).
//  - loop/staging/numerics identical to R13 (bit-identical output).
// ---------------------------------------------------------------------------

typedef __attribute__((ext_vector_type(4))) int int32x4;

__device__ __forceinline__ float bf2f(ushort h) {
    union { unsigned u; float f; } v; v.u = ((unsigned)h) << 16;
    return v.f;
}
constexpr int ilog2(int x) { int r = 0; while (x > 1) { x >>= 1; ++r; } return r; }

__device__ __forceinline__ void gl_lds16(const void* g, void* l) {
    __builtin_amdgcn_global_load_lds(
        (const __attribute__((address_space(1))) unsigned int*)g,
        (__attribute__((address_space(3))) unsigned int*)l, 16, 0, 0);
}

#define SC21 4.76837158203125e-07    // 2^-21  (acts are spikes {0,1})
#define SC23 1.1920928955078125e-07  // 2^-23  (acts are ints 0..4 = 4*act)

// ------------------------------------------------------------ weight prep --
template <int IC, int OC>
__global__ void prep_convw_i8_k(const float* __restrict__ w, char* __restrict__ dst) {
    int idx = blockIdx.x * 256 + threadIdx.x;
    if (idx >= OC * IC * 9) return;
    int oc = idx / (IC * 9);
    int rem = idx % (IC * 9);
    int ic = rem / 9, q = rem % 9;
    int wq_ = (int)rintf(w[idx] * 2097152.0f);   // 2^21 grid
    int a2 = ((wq_ + 128) & 255) - 128;
    int t2 = (wq_ - a2) >> 8;
    int a1 = ((t2 + 128) & 255) - 128;
    int a0 = (t2 - a1) >> 8;
    int sg = ic >> 6, kin = ic & 63, c = kin >> 4, bb = kin & 15;
    int oct = oc >> 6, ocl = oc & 63;
    constexpr int OCT = OC / 64;
    size_t base = ((size_t)(sg * 9 + q) * OCT + oct) * 12288;
    char digs[3] = {(char)a0, (char)a1, (char)a2};
#pragma unroll
    for (int s = 0; s < 3; ++s)
        dst[base + (size_t)(c * 192 + s * 64 + ocl) * 16 + bb] = digs[s];
}

__global__ void prep_fc1w_i8_k(const float* __restrict__ w, char* __restrict__ dst) {
    int idx = blockIdx.x * 256 + threadIdx.x;
    if (idx >= 1024 * 4096) return;
    int j = idx >> 12, k = idx & 4095;
    int c = k >> 4, hw = k & 15;
    int kp = hw * 256 + c;
    int wq_ = (int)rintf(w[idx] * 2097152.0f);
    int a2 = ((wq_ + 128) & 255) - 128;
    int t2 = (wq_ - a2) >> 8;
    int a1 = ((t2 + 128) & 255) - 128;
    int a0 = (t2 - a1) >> 8;
    int slab = kp >> 6, kin = kp & 63, cch = kin >> 4, bb = kin & 15;
    int oct = j >> 6, ocl = j & 63;
    size_t base = ((size_t)(slab * 16 + oct)) * 12288;
    char digs[3] = {(char)a0, (char)a1, (char)a2};
#pragma unroll
    for (int s = 0; s < 3; ++s)
        dst[base + (size_t)(cch * 192 + s * 64 + ocl) * 16 + bb] = digs[s];
}

// ------------------------------------------------------------- halo zero ----
template <int H, int C>
__global__ void halo0_k(char* __restrict__ buf) {
    constexpr int P = 4 * H + 4;
    constexpr int CPI = P * (C / 16);
    int idx = blockIdx.x * 256 + threadIdx.x;
    if (idx >= 1280 * CPI) return;
    int n = idx / CPI, r = idx % CPI;
    int p = r / (C / 16), c16 = r % (C / 16);
    int row, col;
    if (p < 2 * (H + 2)) { row = (p < H + 2) ? 0 : H + 1; col = p % (H + 2); }
    else { int qq = p - 2 * (H + 2); col = (qq < H) ? 0 : H + 1; row = 1 + (qq % H); }
    *(uint4*)&buf[(((size_t)n * (H + 2) + row) * (H + 2) + col) * C + c16 * 16] =
        (uint4){0u, 0u, 0u, 0u};
}

// ------------------------------------------------- conv1 + 10-step LIF ------
__global__ __launch_bounds__(256) void conv1lif_k(const float* __restrict__ inp,
                                                  const float* __restrict__ w1,
                                                  char* __restrict__ act1) {
    __shared__ float ws[27 * 64];
    for (int e = threadIdx.x; e < 1728; e += 256) {
        int oc = e / 27, j = e % 27;
        ws[j * 64 + oc] = w1[e];
    }
    __syncthreads();
    int t = blockIdx.x * 256 + threadIdx.x;
    int q = t & 3;
    int m = t >> 2;
    int n = m >> 10, h = (m >> 5) & 31, w = m & 31;
    float xv[27];
#pragma unroll
    for (int ic = 0; ic < 3; ++ic)
#pragma unroll
        for (int kh = 0; kh < 3; ++kh)
#pragma unroll
            for (int kw = 0; kw < 3; ++kw) {
                int r = h + kh - 1, c = w + kw - 1;
                xv[ic * 9 + kh * 3 + kw] =
                    (r >= 0 && r < 32 && c >= 0 && c < 32)
                        ? inp[(n * 3 + ic) * 1024 + r * 32 + c] : 0.0f;
            }
    float s[16], mem[16];
#pragma unroll
    for (int o = 0; o < 16; ++o) { s[o] = 0.f; mem[o] = 0.f; }
#pragma unroll
    for (int j = 0; j < 27; ++j) {
        float x = xv[j];
        const float* wr = &ws[j * 64 + q * 16];
#pragma unroll
        for (int o = 0; o < 16; ++o) s[o] += wr[o] * x;
    }
    const size_t dbase = (((size_t)h + 1) * 34 + (w + 1)) * 64 + q * 16;
    for (int st = 0; st < 10; ++st) {
        unsigned r[4];
#pragma unroll
        for (int g = 0; g < 4; ++g) {
            unsigned acc = 0;
#pragma unroll
            for (int e = 0; e < 4; ++e) {
                int o = g * 4 + e;
                mem[o] = 0.05f * mem[o] + 0.95f * s[o];
                unsigned b = (mem[o] > 1.f) ? 1u : 0u;
                mem[o] -= (float)b;
                acc |= b << (8 * e);
            }
            r[g] = acc;
        }
        size_t d = ((size_t)(st * 128 + n) * 34 * 34) * 64 + dbase;
        *(uint4*)&act1[d] = (uint4){r[0], r[1], r[2], r[3]};
    }
}

// --------------------------------------------------- i8 implicit-GEMM conv --
// 256 threads / 4 waves (2m x 2n); wave tile 64px x 32oc; MBLK = 128 px.
// EPI: 0 = spike compact, 1 = spike padded.
template <int H, int W, int IC, int OC, int NI, int MR, int EPI>
__global__ __launch_bounds__(256, 3) void convi8_k(const char* __restrict__ act,
                                                   const char* __restrict__ wq,
                                                   char* __restrict__ outs,
                                                   float scale) {
    constexpr int PW = W + 2, PHR = MR + 2;
    constexpr int MBLK = NI * MR * W;
    constexpr int NPIX = NI * PHR * PW;
    constexpr int ACH = NPIX * 4;
    constexpr int HR = (ACH + 255) / 256;
    constexpr int SLABS = IC / 64;
    constexpr int OCT = OC / 64;
    constexpr int U = SLABS * 9;
    constexpr int LHW = ilog2(H * W), LW2 = ilog2(W), LMW = ilog2(MR * W);
    static_assert(MBLK == 128, "tile mapping");

    __shared__ __align__(16) char sA[NPIX * 64];
    __shared__ __align__(16) char sB[2][12288];

    const int tid = threadIdx.x, lane = tid & 63;
    const int wid = tid >> 6;                    // 0..3
    const int wm = wid >> 1, wn = wid & 1;       // 2m x 2n
    const int b = blockIdx.x, oct = blockIdx.y;
    const int oc0 = oct * 64;
    const int m0 = b * MBLK;
    constexpr int TPI = (NI == 1) ? (H / MR) : 1;
    const int n0 = (NI == 1) ? (b / TPI) : (b * NI);
    const int h0 = (NI == 1) ? (b % TPI) * MR : 0;

    int asrc[HR]; bool apred[HR];
#pragma unroll
    for (int r = 0; r < HR; ++r) {
        int i = r * 256 + tid;
        apred[r] = (i < ACH);
        int ii = apred[r] ? i : 0;
        int c = ii / NPIX, pix = ii % NPIX;
        int pc = pix % PW, t2 = pix / PW;
        int hp = t2 % PHR, img = t2 / PHR;
        asrc[r] = (((n0 + img) * (H + 2) + h0 + hp) * PW + pc) * IC + c * 16;
    }
    const int lan15 = lane & 15;
    int apix[4];
#pragma unroll
    for (int am = 0; am < 4; ++am) {
        int p = wm * 64 + am * 16 + lan15;
        int img = p >> LMW;
        int pi = p & ((MR * W) - 1);
        int h = pi >> LW2;
        apix[am] = (img * PHR + h) * PW + (pi & (W - 1));
    }
    const int cA = lane >> 4;

    int32x4 acc[3][4][2];
#pragma unroll
    for (int s = 0; s < 3; ++s)
#pragma unroll
        for (int a = 0; a < 4; ++a)
#pragma unroll
            for (int bn = 0; bn < 2; ++bn) acc[s][a][bn] = (int32x4){0, 0, 0, 0};

    const size_t wqoct = (size_t)oct * 12288;
    constexpr size_t USTRIDE = (size_t)OCT * 12288;

    auto stage_B = [&](int unit, int bufc) {
        const char* wsrc = wq + (size_t)unit * USTRIDE + wqoct + tid * 16;
        char* d = sB[bufc] + tid * 16;
        gl_lds16(wsrc, d);
        gl_lds16(wsrc + 4096, d + 4096);
        gl_lds16(wsrc + 8192, d + 8192);
    };
    auto stage_A = [&](int sl_) {
#pragma unroll
        for (int r = 0; r < HR; ++r)
            if (apred[r]) gl_lds16(act + asrc[r] + sl_ * 64, sA + (r * 256 + tid) * 16);
    };

    stage_A(0);
    stage_B(0, 0);
    __syncthreads();

    int buf = 0;
    for (int u = 0; u < U; ++u) {
        const int q = u - (u / 9) * 9;
        if (u + 1 < U) stage_B(u + 1, buf ^ 1);
        const int qr = q / 3, qc = q - qr * 3;
        int32x4 af[4];
#pragma unroll
        for (int am = 0; am < 4; ++am)
            af[am] = *(const int32x4*)&sA[(cA * NPIX + apix[am] + qr * PW + qc) * 16];
        __builtin_amdgcn_s_setprio(1);
#pragma unroll
        for (int s = 0; s < 3; ++s)
#pragma unroll
            for (int bn = 0; bn < 2; ++bn) {
                int R = s * 64 + wn * 32 + bn * 16 + lan15;
                int32x4 bf = *(const int32x4*)&sB[buf][(cA * 192 + R) * 16];
#pragma unroll
                for (int am = 0; am < 4; ++am)
                    acc[s][am][bn] = __builtin_amdgcn_mfma_i32_16x16x64_i8(
                        af[am], bf, acc[s][am][bn], 0, 0, 0);
            }
        __builtin_amdgcn_s_setprio(0);
        __syncthreads();          // drains stage(u+1); certifies buffer swap
        buf ^= 1;
        if (q == 8 && u + 1 < U) {
            stage_A(u / 9 + 1);   // sA readers retired at the barrier above
            __syncthreads();      // drain halo restage before next tap-0
        }
    }

    const double dscale = (double)scale;
#pragma unroll
    for (int am = 0; am < 4; ++am)
#pragma unroll
        for (int bn = 0; bn < 2; ++bn)
#pragma unroll
            for (int rr = 0; rr < 4; ++rr) {
                int rl = wm * 64 + am * 16 + (lane >> 4) * 4 + rr;
                int col = oc0 + wn * 32 + bn * 16 + lan15;
                int m = m0 + rl;
                long long S = ((long long)acc[0][am][bn][rr] << 16)
                            + ((long long)acc[1][am][bn][rr] << 8)
                            + (long long)acc[2][am][bn][rr];
                float v = (float)((double)S * dscale);
                char sp = (v > 1.0f) ? (char)1 : (char)0;
                if (EPI == 1) {
                    int n = m >> LHW, h = (m >> LW2) & (H - 1), w = m & (W - 1);
                    outs[((size_t)(n * (H + 2) + h + 1) * PW + (w + 1)) * OC + col] = sp;
                } else {
                    outs[(size_t)m * OC + col] = sp;
                }
            }
}

// ------------------------------------------------------------- i8 pool ----
template <int C, int HI>
__global__ void pool_i8_k(const char* __restrict__ in, char* __restrict__ out) {
    constexpr int HO = HI / 2, C16 = C / 16;
    constexpr int TOT = 1280 * HO * HO * C16;
    int idx = blockIdx.x * 256 + threadIdx.x;
    if (idx >= TOT) return;
    int c16 = idx % C16;
    int t = idx / C16;
    int w = t % HO; t /= HO;
    int h = t % HO;
    int n = t / HO;
    const char* p = in + ((size_t)(n * HI + 2 * h) * HI + 2 * w) * C + c16 * 16;
    uint4 a0 = *(const uint4*)p;
    uint4 a1 = *(const uint4*)(p + C);
    uint4 a2 = *(const uint4*)(p + (size_t)HI * C);
    uint4 a3 = *(const uint4*)(p + (size_t)HI * C + C);
    uint4 r;
    r.x = a0.x + a1.x + a2.x + a3.x;
    r.y = a0.y + a1.y + a2.y + a3.y;
    r.z = a0.z + a1.z + a2.z + a3.z;
    r.w = a0.w + a1.w + a2.w + a3.w;
    *(uint4*)&out[((size_t)(n * (HO + 2) + h + 1) * (HO + 2) + (w + 1)) * C + c16 * 16] = r;
}

__global__ void pool3q_k(const char* __restrict__ in, char* __restrict__ out) {
    int idx = blockIdx.x * 256 + threadIdx.x;   // 327680
    if (idx >= 327680) return;
    int c16 = idx & 15;
    int t = idx >> 4;
    int wo = t & 3, ho = (t >> 2) & 3, n = t >> 4;
    const char* p = in + ((size_t)(n * 8 + 2 * ho) * 8 + 2 * wo) * 256 + c16 * 16;
    uint4 a0 = *(const uint4*)p;
    uint4 a1 = *(const uint4*)(p + 256);
    uint4 a2 = *(const uint4*)(p + 2048);
    uint4 a3 = *(const uint4*)(p + 2048 + 256);
    uint4 r;
    r.x = a0.x + a1.x + a2.x + a3.x;
    r.y = a0.y + a1.y + a2.y + a3.y;
    r.z = a0.z + a1.z + a2.z + a3.z;
    r.w = a0.w + a1.w + a2.w + a3.w;
    *(uint4*)&out[((size_t)(n * 16 + ho * 4 + wo) * 16 + c16) * 16] = r;
}

// ----------------------------------------------------------- fc1 i8 GEMM ----
__global__ __launch_bounds__(256) void fc1i8_k(const char* __restrict__ A,
                                               const char* __restrict__ wq,
                                               float* __restrict__ part) {
    __shared__ __align__(16) char sA[2][8192];
    __shared__ __align__(16) char sB[2][12288];
    const int tid = threadIdx.x, lane = tid & 63;
    const int wid = tid >> 6, wm = wid >> 1, wn = wid & 1;
    const int m0 = blockIdx.x * 128, oct = blockIdx.y, kt = blockIdx.z;

    int32x4 acc[3][4][2];
#pragma unroll
    for (int s = 0; s < 3; ++s)
#pragma unroll
        for (int a = 0; a < 4; ++a)
#pragma unroll
            for (int bn = 0; bn < 2; ++bn) acc[s][a][bn] = (int32x4){0, 0, 0, 0};

    auto stageA = [&](int sg, int bf_) {
#pragma unroll
        for (int r = 0; r < 2; ++r) {
            int i = r * 256 + tid;
            int c = i >> 7, pix = i & 127;
            gl_lds16(A + (size_t)(m0 + pix) * 4096 + sg * 64 + c * 16,
                     sA[bf_] + (size_t)i * 16);
        }
    };
    auto stageB = [&](int sg, int bf_) {
        const char* src = wq + ((size_t)(sg * 16 + oct)) * 12288 + tid * 16;
#pragma unroll
        for (int r = 0; r < 3; ++r)
            gl_lds16(src + r * 4096, sB[bf_] + (r * 256 + tid) * 16);
    };

    int buf = 0;
    stageA(kt * 32, 0);
    stageB(kt * 32, 0);
    __syncthreads();
    const int cA = lane >> 4;
    for (int sl = 0; sl < 32; ++sl) {
        int sg = kt * 32 + sl;
        if (sl < 31) { stageA(sg + 1, buf ^ 1); stageB(sg + 1, buf ^ 1); }
        int32x4 af[4];
#pragma unroll
        for (int am = 0; am < 4; ++am)
            af[am] = *(const int32x4*)&sA[buf][(cA * 128 + wm * 64 + am * 16 + (lane & 15)) * 16];
#pragma unroll
        for (int s = 0; s < 3; ++s)
#pragma unroll
            for (int bn = 0; bn < 2; ++bn) {
                int R = s * 64 + wn * 32 + bn * 16 + (lane & 15);
                int32x4 bf = *(const int32x4*)&sB[buf][(cA * 192 + R) * 16];
#pragma unroll
                for (int am = 0; am < 4; ++am)
                    acc[s][am][bn] = __builtin_amdgcn_mfma_i32_16x16x64_i8(
                        af[am], bf, acc[s][am][bn], 0, 0, 0);
            }
        if (sl < 31) { __syncthreads(); buf ^= 1; }
    }
#pragma unroll
    for (int am = 0; am < 4; ++am)
#pragma unroll
        for (int bn = 0; bn < 2; ++bn)
#pragma unroll
            for (int rr = 0; rr < 4; ++rr) {
                int row = m0 + wm * 64 + am * 16 + (lane >> 4) * 4 + rr;
                int col = oct * 64 + wn * 32 + bn * 16 + (lane & 15);
                long long S = ((long long)acc[0][am][bn][rr] << 16)
                            + ((long long)acc[1][am][bn][rr] << 8)
                            + (long long)acc[2][am][bn][rr];
                part[((size_t)kt * 1280 + row) * 1024 + col] = (float)((double)S * SC23);
            }
}

__global__ void fc1lif_k(const float* __restrict__ part, ushort* __restrict__ sbuf) {
    int idx = blockIdx.x * 256 + threadIdx.x;   // 131072
    int n = idx >> 10, j = idx & 1023;
    float m = 0.f;
    for (int t = 0; t < 10; ++t) {
        size_t row = (size_t)(t * 128 + n) * 1024 + j;
        float y = part[row] + part[1310720 + row];
        m = 0.05f * m + 0.95f * y;
        float sp = (m > 1.f) ? 1.f : 0.f;
        m -= sp;
        sbuf[row] = sp > 0.f ? (ushort)0x3F80 : (ushort)0;
    }
}

__global__ __launch_bounds__(256) void fc2o_k(const ushort* __restrict__ S,
                                              const float* __restrict__ W2,
                                              float* __restrict__ out) {
    __shared__ float wsh[10 * 1024];
    __shared__ float red[10][256];
    int n = blockIdx.x, tid = threadIdx.x;
    for (int e = tid; e < 10240; e += 256) wsh[e] = W2[e];
    __syncthreads();
    float accv = 0.f;
    for (int t = 0; t < 10; ++t) {
        const ushort* sp = S + ((size_t)(t * 128 + n)) * 1024 + tid * 4;
        float s0 = bf2f(sp[0]), s1 = bf2f(sp[1]), s2 = bf2f(sp[2]), s3 = bf2f(sp[3]);
#pragma unroll
        for (int o = 0; o < 10; ++o) {
            const float* w = &wsh[o * 1024 + tid * 4];
            red[o][tid] = s0 * w[0] + s1 * w[1] + s2 * w[2] + s3 * w[3];
        }
        __syncthreads();
        for (int off = 128; off >= 1; off >>= 1) {
            if (tid < off) {
#pragma unroll
                for (int o = 0; o < 10; ++o) red[o][tid] += red[o][tid + off];
            }
            __syncthreads();
        }
        if (tid < 10) accv += red[tid][0];
        __syncthreads();
    }
    if (tid < 10) out[n * 10 + tid] = accv * 0.1f;
}

// ---------------------------------------------------------------------------
extern "C" void kernel_launch(void* const* d_in, const int* in_sizes, int n_in,
                              void* d_out, int out_size, void* d_ws, size_t ws_size,
                              hipStream_t stream) {
    const float* inp  = (const float*)d_in[0];
    const float* w1   = (const float*)d_in[1];
    const float* w2   = (const float*)d_in[2];
    const float* w3   = (const float*)d_in[3];
    const float* w4   = (const float*)d_in[4];
    const float* w5   = (const float*)d_in[5];
    const float* w6   = (const float*)d_in[6];
    const float* w7   = (const float*)d_in[7];
    const float* fc1w = (const float*)d_in[8];
    const float* fc2w = (const float*)d_in[9];
    float* out = (float*)d_out;

    char* base = (char*)d_ws;
    char* arenaA = base;                          // 94,679,040 B
    char* arenaB = base + 94679040;               // 83,886,080 B
    size_t o = 94679040 + 83886080;
    auto alloc = [&](size_t bytes) { void* p = base + o; o += (bytes + 255) & ~(size_t)255; return p; };
    char*   wq2  = (char*)alloc(110592);
    char*   wq3  = (char*)alloc(221184);
    char*   wq4  = (char*)alloc(442368);
    char*   wq5  = (char*)alloc(884736);
    char*   wq6  = (char*)alloc(1769472);
    char*   wq7  = (char*)alloc(1769472);
    char*   wqf1 = (char*)alloc(12582912);
    ushort* sbuf = (ushort*)alloc(2621440);
    (void)ws_size;

    char*  act1  = arenaA;                        // [1280][34][34][64]
    char*  c2out = arenaB;                        // [1280][32][32][64]
    char*  act2  = arenaA;                        // [1280][18][18][64]
    char*  c3out = arenaB;                        // [1280][18][18][128]
    char*  c4out = arenaA;                        // [1280][16][16][128]
    char*  act3  = arenaA + 41943040;             // [1280][10][10][128]
    char*  c5out = arenaB;                        // [1280][10][10][256]
    char*  c6out = arenaB + 33554432;             // [1280][10][10][256]
    char*  c7out = arenaA;                        // [1280][8][8][256]
    char*  afc1  = arenaA + 20971520;             // [1280][4096] i8
    float* part  = (float*)(arenaA + 26214400);   // [2][1280][1024] f32

    prep_convw_i8_k<64, 64>  <<<(36864 + 255) / 256, 256, 0, stream>>>(w2, wq2);
    prep_convw_i8_k<64, 128> <<<(73728 + 255) / 256, 256, 0, stream>>>(w3, wq3);
    prep_convw_i8_k<128, 128><<<(147456 + 255) / 256, 256, 0, stream>>>(w4, wq4);
    prep_convw_i8_k<128, 256><<<(294912 + 255) / 256, 256, 0, stream>>>(w5, wq5);
    prep_convw_i8_k<256, 256><<<(589824 + 255) / 256, 256, 0, stream>>>(w6, wq6);
    prep_convw_i8_k<256, 256><<<(589824 + 255) / 256, 256, 0, stream>>>(w7, wq7);
    prep_fc1w_i8_k<<<(4194304 + 255) / 256, 256, 0, stream>>>(fc1w, wqf1);

    halo0_k<32, 64><<<(1280 * 132 * 4 + 255) / 256, 256, 0, stream>>>(act1);
    conv1lif_k<<<2048, 256, 0, stream>>>(inp, w1, act1);

    convi8_k<32, 32, 64, 64, 1, 4, 0>
        <<<dim3(10240, 1), 256, 0, stream>>>(act1, wq2, c2out, (float)SC21);
    halo0_k<16, 64><<<(1280 * 68 * 4 + 255) / 256, 256, 0, stream>>>(act2);
    pool_i8_k<64, 32><<<(1280 * 256 * 4 + 255) / 256, 256, 0, stream>>>(c2out, act2);

    halo0_k<16, 128><<<(1280 * 68 * 8 + 255) / 256, 256, 0, stream>>>(c3out);
    convi8_k<16, 16, 64, 128, 1, 8, 1>
        <<<dim3(2560, 2), 256, 0, stream>>>(act2, wq3, c3out, (float)SC23);
    convi8_k<16, 16, 128, 128, 1, 8, 0>
        <<<dim3(2560, 2), 256, 0, stream>>>(c3out, wq4, c4out, (float)SC21);
    halo0_k<8, 128><<<(1280 * 36 * 8 + 255) / 256, 256, 0, stream>>>(act3);
    pool_i8_k<128, 16><<<(1280 * 64 * 8 + 255) / 256, 256, 0, stream>>>(c4out, act3);

    halo0_k<8, 256><<<(1280 * 36 * 16 + 255) / 256, 256, 0, stream>>>(c5out);
    convi8_k<8, 8, 128, 256, 2, 8, 1>
        <<<dim3(640, 4), 256, 0, stream>>>(act3, wq5, c5out, (float)SC23);
    halo0_k<8, 256><<<(1280 * 36 * 16 + 255) / 256, 256, 0, stream>>>(c6out);
    convi8_k<8, 8, 256, 256, 2, 8, 1>
        <<<dim3(640, 4), 256, 0, stream>>>(c5out, wq6, c6out, (float)SC21);
    convi8_k<8, 8, 256, 256, 2, 8, 0>
        <<<dim3(640, 4), 256, 0, stream>>>(c6out, wq7, c7out, (float)SC21);

    pool3q_k<<<(327680 + 255) / 256, 256, 0, stream>>>(c7out, afc1);

    fc1i8_k<<<dim3(10, 16, 2), 256, 0, stream>>>(afc1, wqf1, part);
    fc1lif_k<<<512, 256, 0, stream>>>(part, sbuf);
    fc2o_k<<<128, 256, 0, stream>>>(sbuf, fc2w, out);
}